// Round 3
// baseline (419.306 us; speedup 1.0000x reference)
//
#include <hip/hip_runtime.h>

// CapsNet routing: N=32, C=32, D=16(=P*P), S=W*H=256, K=10, n_rout=3.
// One kernel launch per routing iteration; per-n cross-block coupling via
// non-atomic partial buffer + per-n arrival counter ("last block" pattern).
// No cooperative launch (R2's grid-wide coop launch was rejected -> no-op).

#define KK 10
#define PP 16
#define CC 32
#define SS 256
#define NN 32

__global__ __launch_bounds__(256) void zero_kernel(int* __restrict__ counter) {
  if (threadIdx.x < 3 * NN) counter[threadIdx.x] = 0;
}

__global__ __launch_bounds__(256, 4) void iter_kernel(
    const float* __restrict__ l,       // [N][C][16][256]
    const float* __restrict__ w,       // [C][K][4][4]
    const float* __restrict__ vec_in,  // [N][K][16]  (g on iter 0, else gc_buf)
    float* __restrict__ sp_buf,        // [N][C][160] per-block s-partials
    int* __restrict__ counter,         // [N] arrival counters (this iter's slice)
    float* __restrict__ gc_buf,        // [N][K][16]  next iter's vec
    float* __restrict__ out_a,         // [N][K]
    float* __restrict__ out_gc,        // [N][K][16]
    const int last)
{
  const int bid = blockIdx.x;
  const int n = bid >> 5;
  const int c = bid & 31;
  const int t = threadIdx.x;

  __shared__ float lr_lds[PP][SS + 4];   // [ij][s]
  __shared__ float ct[KK][SS + 4];       // softmax weights [k][s]
  __shared__ float U_lds[KK * PP];       // U, later reused for M, later for s
  __shared__ float w_lds[KK * PP];       // w[c]
  __shared__ float vec_lds[KK * PP];     // g or gc
  __shared__ float wp[4][KK][PP];        // per-wave M partials
  __shared__ float f_lds[KK];
  __shared__ int   flag;

  // ---- phase 1: stage inputs ----
  if (t < KK * PP) {
    w_lds[t]   = w[c * KK * PP + t];
    vec_lds[t] = vec_in[n * KK * PP + t];
  }
  float lr[PP];
  const float* lb = l + (size_t)(n * CC + c) * (PP * SS) + t;
  #pragma unroll
  for (int d = 0; d < PP; ++d) {
    lr[d] = lb[d * SS];                 // coalesced across threads
    lr_lds[d][t] = lr[d];
  }
  __syncthreads();

  // ---- phase 2: U[k][i*4+j] = sum_dd w[c,k,j,dd]*vec[k,i*4+dd] ----
  if (t < KK * PP) {
    const int k = t >> 4, ij = t & 15, i = ij >> 2, j = ij & 3;
    const float* wpt = w_lds + k * PP + j * 4;
    const float* vpt = vec_lds + k * PP + i * 4;
    U_lds[t] = wpt[0]*vpt[0] + wpt[1]*vpt[1] + wpt[2]*vpt[2] + wpt[3]*vpt[3];
  }
  __syncthreads();

  // ---- phase 3: b[k] = lr . U[k], softmax over k ----
  {
    float b[KK];
    float bmax = -1e30f;
    #pragma unroll
    for (int k = 0; k < KK; ++k) {
      float acc = 0.f;
      #pragma unroll
      for (int d4 = 0; d4 < 4; ++d4) {
        const float4 uv = *(const float4*)&U_lds[k * PP + d4 * 4];  // broadcast
        acc += lr[d4*4+0]*uv.x + lr[d4*4+1]*uv.y + lr[d4*4+2]*uv.z + lr[d4*4+3]*uv.w;
      }
      b[k] = acc;
      bmax = fmaxf(bmax, acc);
    }
    float ssum = 0.f;
    #pragma unroll
    for (int k = 0; k < KK; ++k) { b[k] = __expf(b[k] - bmax); ssum += b[k]; }
    const float inv = 1.f / ssum;
    #pragma unroll
    for (int k = 0; k < KK; ++k) ct[k][t] = b[k] * inv;
  }
  __syncthreads();

  // ---- phase 4: M[k][ij] = sum_s ct[k][s]*lr[ij][s], chunked over all 256 thr
  {
    const int ch = t >> 4;       // 16 chunks of 16 s-values
    const int ij = t & 15;
    const int sbase = ch * 16;
    float acc[KK];
    #pragma unroll
    for (int k = 0; k < KK; ++k) acc[k] = 0.f;
    #pragma unroll
    for (int s4 = 0; s4 < 4; ++s4) {
      const float4 lv = *(const float4*)&lr_lds[ij][sbase + s4 * 4];
      #pragma unroll
      for (int k = 0; k < KK; ++k) {
        const float4 cv = *(const float4*)&ct[k][sbase + s4 * 4];
        acc[k] += cv.x*lv.x + cv.y*lv.y + cv.z*lv.z + cv.w*lv.w;
      }
    }
    const int lane = t & 63;
    #pragma unroll
    for (int k = 0; k < KK; ++k) {
      float v = acc[k];
      v += __shfl_xor(v, 16, 64);    // sum chunk bit0 within wave
      v += __shfl_xor(v, 32, 64);    // sum chunk bit1 within wave
      if (lane < 16) wp[t >> 6][k][lane] = v;
    }
  }
  __syncthreads();

  // ---- phase 5: merge wave partials -> M (stored in U_lds) ----
  if (t < KK * PP) {
    const int k = t >> 4, ij = t & 15;
    U_lds[t] = wp[0][k][ij] + wp[1][k][ij] + wp[2][k][ij] + wp[3][k][ij];
  }
  __syncthreads();

  // ---- phase 6: s-partial[k][i*4+d] = sum_j M[k][i*4+j]*w[c,k,j,d] ----
  if (t < KK * PP) {
    const int k = t >> 4, i = (t >> 2) & 3, d = t & 3;
    const float* Mp  = U_lds + k * PP + i * 4;
    const float* wpt = w_lds + k * PP + d;
    const float sv = Mp[0]*wpt[0] + Mp[1]*wpt[4] + Mp[2]*wpt[8] + Mp[3]*wpt[12];
    sp_buf[(n * CC + c) * (KK * PP) + t] = sv;
  }
  __threadfence();                       // release sp writes
  if (t == 0) flag = (atomicAdd(&counter[n], 1) == CC - 1);
  __syncthreads();
  if (!flag) return;

  // ---- last block of this n: reduce over c, squash, emit ----
  __threadfence();                       // acquire sp writes
  if (t < KK * PP) {
    float sv = 0.f;
    #pragma unroll
    for (int c2 = 0; c2 < CC; ++c2) sv += sp_buf[(n * CC + c2) * (KK * PP) + t];
    U_lds[t] = sv;
  }
  __syncthreads();
  if (t < KK) {
    float sn = 0.f;
    #pragma unroll
    for (int m = 0; m < PP; ++m) { const float v = U_lds[t * PP + m]; sn += v * v; }
    f_lds[t] = sn / (1.f + sn) * rsqrtf(sn);
    if (last) {
      const float gn = sn / (1.f + sn);  // = sqrt(sum gc^2)
      out_a[n * KK + t] = 1.f / (1.f + __expf(-gn));
    }
  }
  __syncthreads();
  if (t < KK * PP) {
    const float gv = U_lds[t] * f_lds[t >> 4];
    gc_buf[n * KK * PP + t] = gv;
    if (last) out_gc[n * KK * PP + t] = gv;
  }
}

extern "C" void kernel_launch(void* const* d_in, const int* in_sizes, int n_in,
                              void* d_out, int out_size, void* d_ws, size_t ws_size,
                              hipStream_t stream) {
  const float* l = (const float*)d_in[0];
  const float* g = (const float*)d_in[1];
  const float* w = (const float*)d_in[2];

  float* out    = (float*)d_out;
  float* out_a  = out;
  float* out_gc = out + NN * KK;

  float* sp_buf  = (float*)d_ws;                       // 1024*160 floats
  float* gc_buf  = sp_buf + NN * CC * KK * PP;         // 32*160 floats
  int*   counter = (int*)(gc_buf + NN * KK * PP);      // 3*32 ints

  zero_kernel<<<1, 256, 0, stream>>>(counter);
  iter_kernel<<<NN * CC, 256, 0, stream>>>(l, w, g,      sp_buf, counter + 0*NN,
                                           gc_buf, out_a, out_gc, 0);
  iter_kernel<<<NN * CC, 256, 0, stream>>>(l, w, gc_buf, sp_buf, counter + 1*NN,
                                           gc_buf, out_a, out_gc, 0);
  iter_kernel<<<NN * CC, 256, 0, stream>>>(l, w, gc_buf, sp_buf, counter + 2*NN,
                                           gc_buf, out_a, out_gc, 1);
}

// Round 4
// 89.456 us; speedup vs baseline: 4.6873x; 4.6873x over previous
//
#include <hip/hip_runtime.h>

// CapsNet routing: N=32, C=32, D=16(=P*P), S=W*H=256, K=10, n_rout=3.
// 5 graph nodes: memset(s_buf) + 3x iter_kernel + final_kernel.
// Cross-block coupling ONLY at kernel boundaries (no device fences -- R3's
// per-wave __threadfence caused L2 wb/inv storms: 130us/kernel at 2.7% VALU).
// s accumulated via device atomicAdd into pre-zeroed s_buf[r].

#define KK 10
#define PP 16
#define CC 32
#define SS 256
#define NN 32

__global__ __launch_bounds__(256, 4) void iter_kernel(
    const float* __restrict__ l,       // [N][C][16][256]
    const float* __restrict__ w,       // [C][K][4][4]
    const float* __restrict__ g,       // [N][K][16]   (used when first)
    const float* __restrict__ s_prev,  // [N][K*16]    (used when !first)
    float* __restrict__ s_next,        // [N][K*16]    atomic accumulate
    const int first)
{
  const int bid = blockIdx.x;
  const int n = bid >> 5;
  const int c = bid & 31;
  const int t = threadIdx.x;           // t == s in phases 3-4

  __shared__ float lr_lds[PP][SS + 4];     // [ij][s]
  __shared__ float ct[KK][SS + 4];         // softmax weights [k][s]
  __shared__ float U_lds[KK * PP];         // U; reused for M in phase 6
  __shared__ float w_lds[KK * PP];         // w[c]
  __shared__ float gc_lds[KK * PP];        // g or squash(s_prev)
  __shared__ float f_lds[KK];
  __shared__ float part[KK][PP][PP + 1];   // per-chunk M partials, padded

  // ---- stage w[c] and l slice ----
  if (t < KK * PP) w_lds[t] = w[c * KK * PP + t];
  float lr[PP];
  const float* lb = l + (size_t)(n * CC + c) * (PP * SS) + t;
  #pragma unroll
  for (int d = 0; d < PP; ++d) {
    lr[d] = lb[d * SS];                 // coalesced across t
    lr_lds[d][t] = lr[d];
  }

  // ---- vec = g (iter 0) or squash(s_prev) ----
  if (first) {
    if (t < KK * PP) gc_lds[t] = g[n * KK * PP + t];
    __syncthreads();
  } else {
    if (t < KK * PP) gc_lds[t] = s_prev[n * KK * PP + t];
    __syncthreads();
    if (t < KK) {
      float sn = 0.f;
      #pragma unroll
      for (int m = 0; m < PP; ++m) { const float v = gc_lds[t * PP + m]; sn += v * v; }
      f_lds[t] = sn / (1.f + sn) * rsqrtf(sn);
    }
    __syncthreads();
    if (t < KK * PP) gc_lds[t] *= f_lds[t >> 4];
    __syncthreads();
  }

  // ---- U[k][i*4+j] = sum_dd w[c,k,j,dd] * gc[k,i*4+dd] ----
  if (t < KK * PP) {
    const int k = t >> 4, ij = t & 15, i = ij >> 2, j = ij & 3;
    const float4 wv = *(const float4*)&w_lds[k * PP + j * 4];
    const float4 gv = *(const float4*)&gc_lds[k * PP + i * 4];
    U_lds[t] = wv.x * gv.x + wv.y * gv.y + wv.z * gv.z + wv.w * gv.w;
  }
  __syncthreads();

  // ---- b[k] = lr . U[k]; softmax over k; store ct[k][s] ----
  {
    float b[KK];
    float bmax = -1e30f;
    #pragma unroll
    for (int k = 0; k < KK; ++k) {
      float acc = 0.f;
      #pragma unroll
      for (int d4 = 0; d4 < 4; ++d4) {
        const float4 uv = *(const float4*)&U_lds[k * PP + d4 * 4];  // wave-uniform addr: broadcast
        acc += lr[d4*4+0]*uv.x + lr[d4*4+1]*uv.y + lr[d4*4+2]*uv.z + lr[d4*4+3]*uv.w;
      }
      b[k] = acc;
      bmax = fmaxf(bmax, acc);
    }
    float ssum = 0.f;
    #pragma unroll
    for (int k = 0; k < KK; ++k) { b[k] = __expf(b[k] - bmax); ssum += b[k]; }
    const float inv = 1.f / ssum;
    #pragma unroll
    for (int k = 0; k < KK; ++k) ct[k][t] = b[k] * inv;
  }
  __syncthreads();

  // ---- M[k][ij] = sum_s ct[k][s]*lr[ij][s]: 256 thr, 16-s chunks, reg accs ----
  {
    const int ch = t >> 4;        // 16 chunks of 16 s
    const int ij = t & 15;
    const int sbase = ch * 16;
    float acc[KK];
    #pragma unroll
    for (int k = 0; k < KK; ++k) acc[k] = 0.f;
    #pragma unroll
    for (int s4 = 0; s4 < 4; ++s4) {
      const float4 lv = *(const float4*)&lr_lds[ij][sbase + s4 * 4];
      #pragma unroll
      for (int k = 0; k < KK; ++k) {
        const float4 cv = *(const float4*)&ct[k][sbase + s4 * 4];   // 4 addrs/wave: broadcast-ish
        acc[k] += cv.x*lv.x + cv.y*lv.y + cv.z*lv.z + cv.w*lv.w;
      }
    }
    #pragma unroll
    for (int k = 0; k < KK; ++k) part[k][ij][ch] = acc[k];
  }
  __syncthreads();

  // ---- merge chunk partials -> M (into U_lds) ----
  if (t < KK * PP) {
    const int k = t >> 4, ij = t & 15;
    float m = 0.f;
    #pragma unroll
    for (int s4 = 0; s4 < 4; ++s4) {
      const float4 pv = *(const float4*)&part[k][ij][s4 * 4];
      m += pv.x + pv.y + pv.z + pv.w;
    }
    U_lds[t] = m;   // U dead; now holds M
  }
  __syncthreads();

  // ---- s-partial[k][i*4+d] = sum_j M[k][i*4+j]*w[c,k,j,d]; atomic accumulate ----
  if (t < KK * PP) {
    const int k = t >> 4, i = (t >> 2) & 3, d = t & 3;
    const float* Mp  = U_lds + k * PP + i * 4;
    const float* wpt = w_lds + k * PP + d;
    const float sv = Mp[0]*wpt[0] + Mp[1]*wpt[4] + Mp[2]*wpt[8] + Mp[3]*wpt[12];
    atomicAdd(&s_next[n * KK * PP + t], sv);
  }
}

__global__ __launch_bounds__(256) void final_kernel(
    const float* __restrict__ s_last,  // [N][K*16]
    float* __restrict__ out_a,         // [N][K]
    float* __restrict__ out_gc)        // [N][K][16]
{
  const int n = blockIdx.x;
  const int t = threadIdx.x;
  __shared__ float s_lds[KK * PP];
  __shared__ float f_lds[KK];
  if (t < KK * PP) s_lds[t] = s_last[n * KK * PP + t];
  __syncthreads();
  if (t < KK) {
    float sn = 0.f;
    #pragma unroll
    for (int m = 0; m < PP; ++m) { const float v = s_lds[t * PP + m]; sn += v * v; }
    f_lds[t] = sn / (1.f + sn) * rsqrtf(sn);
    const float gn = sn / (1.f + sn);          // = sqrt(sum gc^2)
    out_a[n * KK + t] = 1.f / (1.f + __expf(-gn));
  }
  __syncthreads();
  if (t < KK * PP) out_gc[n * KK * PP + t] = s_lds[t] * f_lds[t >> 4];
}

extern "C" void kernel_launch(void* const* d_in, const int* in_sizes, int n_in,
                              void* d_out, int out_size, void* d_ws, size_t ws_size,
                              hipStream_t stream) {
  const float* l = (const float*)d_in[0];
  const float* g = (const float*)d_in[1];
  const float* w = (const float*)d_in[2];

  float* out    = (float*)d_out;
  float* out_a  = out;
  float* out_gc = out + NN * KK;

  float* s_buf = (float*)d_ws;                 // [3][N][160]
  const size_t s_bytes = (size_t)3 * NN * KK * PP * sizeof(float);
  hipMemsetAsync(s_buf, 0, s_bytes, stream);

  float* s0 = s_buf;
  float* s1 = s_buf + NN * KK * PP;
  float* s2 = s_buf + 2 * NN * KK * PP;

  iter_kernel<<<NN * CC, 256, 0, stream>>>(l, w, g, (const float*)nullptr, s0, 1);
  iter_kernel<<<NN * CC, 256, 0, stream>>>(l, w, g, s0, s1, 0);
  iter_kernel<<<NN * CC, 256, 0, stream>>>(l, w, g, s1, s2, 0);
  final_kernel<<<NN, 256, 0, stream>>>(s2, out_a, out_gc);
}